// Round 3
// baseline (249.780 us; speedup 1.0000x reference)
//
#include <hip/hip_runtime.h>

// StrictProjectionBlock: per-3x3-matrix Frobenius normalize + 4 Newton-Schulz
// layers. dur_us = ~173us harness poison fills (fixed) + kernel.
// R4 (block-synchronous, global_load_lds w=16): PASSED, kernel ~88us,
//   VGPR=20, VALUBusy 36%, HBM 30%, occupancy 63% -> stall-bound (barrier
//   drains vmcnt(0) + 61 short blocks/CU churn).
// R5 (persistent barrier-free, global_load_lds w=12 + hand-counted vmcnt):
//   FAILED absmax~5. Post-mortem: 12B DMA width is HW-unverified (only 4B/16B
//   measured); suspected LDS lane-stride mismatch scrambles the tile.
//
// R6: keep R5's architecture, drop every unverified mechanism.
//  * Persistent: 2048 blocks x 256 = 8 blocks/CU all-resident, no churn.
//  * Zero barriers: each wave owns a private 2 x 2304B LDS double buffer and
//    a private tile stream (tile = 64 matrices, t = gw + k*8192, n = 7 or 8).
//    All LDS hazards are wave-local -> HW in-order LDS + compiler lgkmcnt is
//    conservative-correct. Divergent trip counts are safe (no coupling).
//  * Staging via REGISTERS (T14 issue-early / write-late): at top of iter k,
//    issue tile k+1's 3 global_load_dwordx4 into v4f regs; compute tile k
//    from LDS; at the bottom ds_write the regs into the other buffer. The
//    compiler's own vmcnt wait for the prefetch then sits AFTER the compute,
//    hiding HBM latency. No inline asm, no manual counting anywhere.
//  * Nontemporal v4f output stores (don't evict L3-resident input between
//    graph replays).
// Math unchanged (R2): Q' = Q*M, M = (0.5N-1.5I)N + 2I, symmetric (6 scalars).
// LDS per-thread stride-9 access: bank permutation (gcd(9,32)=1) -> only the
// free 2-way wave64 aliasing (R1 measured SQ_LDS_BANK_CONFLICT = 0).

#define NLAYERS 4
#define GRID_BLOCKS 2048
#define WPB 4
#define TOTAL_WAVES (GRID_BLOCKS * WPB)   // 8192
#define WFLOATS 576                        // 64 matrices * 9 floats per tile

typedef float v4f __attribute__((ext_vector_type(4)));

__global__ __launch_bounds__(256, 8) void
proj_kernel(const float* __restrict__ x, float* __restrict__ out, int nwt) {
    __shared__ float lds[2][WPB][WFLOATS];   // 2*4*576*4 = 18432 B
    const int tid  = threadIdx.x;
    const int lane = tid & 63;
    const int w    = tid >> 6;
    const int gw   = blockIdx.x * WPB + w;   // global wave id, 0..8191

    // tiles for this wave (wave-uniform trip count, 7 or 8)
    const int n = (nwt - gw + TOTAL_WAVES - 1) / TOTAL_WAVES;
    if (n <= 0) return;

    // named pointers, swapped explicitly (rule #20: no runtime-indexed arrays)
    float* cur = &lds[0][w][0];
    float* nxt = &lds[1][w][0];

    // ---- prologue: stage tile 0 through registers into cur ----
    {
        const v4f* g4 = (const v4f*)(x + (long long)gw * WFLOATS);
        v4f r0 = g4[lane];
        v4f r1 = g4[lane + 64];
        v4f r2;
        if (lane < 16) r2 = g4[lane + 128];
        v4f* l4 = (v4f*)cur;
        l4[lane]      = r0;
        l4[lane + 64] = r1;
        if (lane < 16) l4[lane + 128] = r2;
    }

    for (int k = 0; k < n; ++k) {
        const long long t = gw + (long long)k * TOTAL_WAVES;
        const bool has_next = (k + 1 < n);

        // ---- issue tile k+1's global loads NOW (consumed at loop bottom) ----
        v4f p0, p1, p2;
        if (has_next) {
            const v4f* g4n = (const v4f*)(x + (t + TOTAL_WAVES) * WFLOATS);
            p0 = g4n[lane];
            p1 = g4n[lane + 64];
            if (lane < 16) p2 = g4n[lane + 128];
        }

        // ---- per-thread matrix from own wave region (stride-9) ----
        float q[9];
#pragma unroll
        for (int j = 0; j < 9; ++j) q[j] = cur[lane * 9 + j];

        // ---- Frobenius normalize ----
        float s = 0.f;
#pragma unroll
        for (int j = 0; j < 9; ++j) s = __builtin_fmaf(q[j], q[j], s);
        const float inv = rsqrtf(s);
#pragma unroll
        for (int j = 0; j < 9; ++j) q[j] *= inv;

        // ---- 4 Newton-Schulz layers: Q <- Q * ((0.5N - 1.5I)N + 2I) ----
#pragma unroll
        for (int layer = 0; layer < NLAYERS; ++layer) {
            const float n00 = q[0]*q[0] + q[3]*q[3] + q[6]*q[6];
            const float n01 = q[0]*q[1] + q[3]*q[4] + q[6]*q[7];
            const float n02 = q[0]*q[2] + q[3]*q[5] + q[6]*q[8];
            const float n11 = q[1]*q[1] + q[4]*q[4] + q[7]*q[7];
            const float n12 = q[1]*q[2] + q[4]*q[5] + q[7]*q[8];
            const float n22 = q[2]*q[2] + q[5]*q[5] + q[8]*q[8];

            const float a00 = __builtin_fmaf(0.5f, n00, -1.5f);
            const float a11 = __builtin_fmaf(0.5f, n11, -1.5f);
            const float a22 = __builtin_fmaf(0.5f, n22, -1.5f);
            const float a01 = 0.5f * n01;
            const float a02 = 0.5f * n02;
            const float a12 = 0.5f * n12;

            const float m00 = __builtin_fmaf(a00,n00, __builtin_fmaf(a01,n01, __builtin_fmaf(a02,n02, 2.0f)));
            const float m01 = __builtin_fmaf(a00,n01, __builtin_fmaf(a01,n11, a02*n12));
            const float m02 = __builtin_fmaf(a00,n02, __builtin_fmaf(a01,n12, a02*n22));
            const float m11 = __builtin_fmaf(a01,n01, __builtin_fmaf(a11,n11, __builtin_fmaf(a12,n12, 2.0f)));
            const float m12 = __builtin_fmaf(a01,n02, __builtin_fmaf(a11,n12, a12*n22));
            const float m22 = __builtin_fmaf(a02,n02, __builtin_fmaf(a12,n12, __builtin_fmaf(a22,n22, 2.0f)));

            float qn[9];
#pragma unroll
            for (int i = 0; i < 3; ++i) {
                const float q0 = q[3*i], q1 = q[3*i+1], q2 = q[3*i+2];
                qn[3*i+0] = __builtin_fmaf(q0, m00, __builtin_fmaf(q1, m01, q2 * m02));
                qn[3*i+1] = __builtin_fmaf(q0, m01, __builtin_fmaf(q1, m11, q2 * m12));
                qn[3*i+2] = __builtin_fmaf(q0, m02, __builtin_fmaf(q1, m12, q2 * m22));
            }
#pragma unroll
            for (int j = 0; j < 9; ++j) q[j] = qn[j];
        }

        // ---- in-place write-back (thread-private 36B), then coalesced
        //      nontemporal v4f stores. Wave-local ds_write->ds_read ordering
        //      is handled by the compiler's conservative lgkmcnt waits. ----
#pragma unroll
        for (int j = 0; j < 9; ++j) cur[lane * 9 + j] = q[j];
        {
            const v4f* l4 = (const v4f*)cur;
            v4f* g4 = (v4f*)(out + t * WFLOATS);
            __builtin_nontemporal_store(l4[lane],      g4 + lane);
            __builtin_nontemporal_store(l4[lane + 64], g4 + lane + 64);
            if (lane < 16)
                __builtin_nontemporal_store(l4[lane + 128], g4 + lane + 128);
        }

        // ---- write-late: commit the prefetched tile into the other buffer.
        //      The compiler's vmcnt wait for p0..p2 lands HERE (post-compute),
        //      so the HBM latency was hidden under the NS iterations. ----
        if (has_next) {
            v4f* l4n = (v4f*)nxt;
            l4n[lane]      = p0;
            l4n[lane + 64] = p1;
            if (lane < 16) l4n[lane + 128] = p2;
            float* tmp = cur; cur = nxt; nxt = tmp;
        }
    }
}

extern "C" void kernel_launch(void* const* d_in, const int* in_sizes, int n_in,
                              void* d_out, int out_size, void* d_ws, size_t ws_size,
                              hipStream_t stream) {
    const float* x = (const float*)d_in[0];
    float* out = (float*)d_out;
    const int nmat = in_sizes[0] / 9;        // 4,000,000
    const int nwt = nmat / 64;               // 62,500 wave-tiles (exact)
    proj_kernel<<<GRID_BLOCKS, 256, 0, stream>>>(x, out, nwt);
}

// Round 4
// 247.333 us; speedup vs baseline: 1.0099x; 1.0099x over previous
//
#include <hip/hip_runtime.h>

// StrictProjectionBlock: per-3x3-matrix Frobenius normalize + 4 Newton-Schulz
// layers. dur_us = ~173us harness poison fills (fixed) + kernel.
// History:
//  R4 block-sync + global_load_lds w16: 88us. VALU 36%, HBM 30%, occ 63%.
//  R5 persistent + w12 DMA + hand vmcnt: FAILED (12B DMA width unverified).
//  R6 persistent barrier-free reg-staged: PASSED but NEUTRAL (88us, VALU 35%,
//     occ 58%, VGPR=32 -> compiler sank the prefetch; pipeline never existed).
//  Conclusion: not barriers, not churn (fills hit 83% peak with short blocks),
//  not occupancy-cap. Remaining shared suspect: the LDS round-trip itself
//  (9 ds_read + 9 ds_write + staging + lgkm serialization per thread-tile).
//
// R7: ABLATE LDS ENTIRELY. One matrix per thread, direct strided access:
//  * loads: 2 x global_load_dwordx4 + 1 x dword at stride 36B (dword-aligned
//    vector loads are legal; a wave's loads cover one contiguous 2304B span,
//    L1 absorbs the ~3x line re-touches; requested bytes unchanged).
//  * stores: same shape, NORMAL stores (not nontemporal: partial-line NT
//    writes would reach HBM unmerged; cached writes assemble full lines in
//    L2 -> WRITE_SIZE should stay ~144MB. If it balloons, revert this).
//  * no LDS, no barriers, no inline asm, no waits beyond compiler vmcnt.
//  * __launch_bounds__(256,8): <=64 VGPR, up to 32 waves/CU of pure TLP.
//  * exact launch 15625 blocks x 256, one matrix per thread, no loop.
// Math unchanged (R2): Q' = Q*M, M = (0.5N-1.5I)N + 2I, symmetric (6 scalars).

#define NLAYERS 4

// 4-byte-aligned float4: compiler emits global_load_dwordx4 with align 4.
typedef float v4fu __attribute__((ext_vector_type(4), aligned(4)));

__global__ __launch_bounds__(256, 8) void
proj_kernel(const float* __restrict__ x, float* __restrict__ out) {
    const long long gid = (long long)blockIdx.x * 256 + threadIdx.x;
    const float* __restrict__ src = x + gid * 9;

    // ---- direct strided load: 9 floats = x4 + x4 + dword ----
    float q[9];
    {
        const v4fu a = *(const v4fu*)(src);
        const v4fu b = *(const v4fu*)(src + 4);
        const float c = src[8];
        q[0] = a.x; q[1] = a.y; q[2] = a.z; q[3] = a.w;
        q[4] = b.x; q[5] = b.y; q[6] = b.z; q[7] = b.w;
        q[8] = c;
    }

    // ---- Frobenius normalize ----
    float s = 0.f;
#pragma unroll
    for (int j = 0; j < 9; ++j) s = __builtin_fmaf(q[j], q[j], s);
    const float inv = rsqrtf(s);
#pragma unroll
    for (int j = 0; j < 9; ++j) q[j] *= inv;

    // ---- 4 Newton-Schulz layers: Q <- Q * ((0.5N - 1.5I)N + 2I) ----
#pragma unroll
    for (int layer = 0; layer < NLAYERS; ++layer) {
        const float n00 = q[0]*q[0] + q[3]*q[3] + q[6]*q[6];
        const float n01 = q[0]*q[1] + q[3]*q[4] + q[6]*q[7];
        const float n02 = q[0]*q[2] + q[3]*q[5] + q[6]*q[8];
        const float n11 = q[1]*q[1] + q[4]*q[4] + q[7]*q[7];
        const float n12 = q[1]*q[2] + q[4]*q[5] + q[7]*q[8];
        const float n22 = q[2]*q[2] + q[5]*q[5] + q[8]*q[8];

        const float a00 = __builtin_fmaf(0.5f, n00, -1.5f);
        const float a11 = __builtin_fmaf(0.5f, n11, -1.5f);
        const float a22 = __builtin_fmaf(0.5f, n22, -1.5f);
        const float a01 = 0.5f * n01;
        const float a02 = 0.5f * n02;
        const float a12 = 0.5f * n12;

        const float m00 = __builtin_fmaf(a00,n00, __builtin_fmaf(a01,n01, __builtin_fmaf(a02,n02, 2.0f)));
        const float m01 = __builtin_fmaf(a00,n01, __builtin_fmaf(a01,n11, a02*n12));
        const float m02 = __builtin_fmaf(a00,n02, __builtin_fmaf(a01,n12, a02*n22));
        const float m11 = __builtin_fmaf(a01,n01, __builtin_fmaf(a11,n11, __builtin_fmaf(a12,n12, 2.0f)));
        const float m12 = __builtin_fmaf(a01,n02, __builtin_fmaf(a11,n12, a12*n22));
        const float m22 = __builtin_fmaf(a02,n02, __builtin_fmaf(a12,n12, __builtin_fmaf(a22,n22, 2.0f)));

        float qn[9];
#pragma unroll
        for (int i = 0; i < 3; ++i) {
            const float q0 = q[3*i], q1 = q[3*i+1], q2 = q[3*i+2];
            qn[3*i+0] = __builtin_fmaf(q0, m00, __builtin_fmaf(q1, m01, q2 * m02));
            qn[3*i+1] = __builtin_fmaf(q0, m01, __builtin_fmaf(q1, m11, q2 * m12));
            qn[3*i+2] = __builtin_fmaf(q0, m02, __builtin_fmaf(q1, m12, q2 * m22));
        }
#pragma unroll
        for (int j = 0; j < 9; ++j) q[j] = qn[j];
    }

    // ---- direct strided store: x4 + x4 + dword (normal, L2-merged) ----
    float* __restrict__ dst = out + gid * 9;
    {
        v4fu a, b;
        a.x = q[0]; a.y = q[1]; a.z = q[2]; a.w = q[3];
        b.x = q[4]; b.y = q[5]; b.z = q[6]; b.w = q[7];
        *(v4fu*)(dst)     = a;
        *(v4fu*)(dst + 4) = b;
        dst[8] = q[8];
    }
}

extern "C" void kernel_launch(void* const* d_in, const int* in_sizes, int n_in,
                              void* d_out, int out_size, void* d_ws, size_t ws_size,
                              hipStream_t stream) {
    const float* x = (const float*)d_in[0];
    float* out = (float*)d_out;
    const int nmat = in_sizes[0] / 9;        // 4,000,000
    const int blocks = nmat / 256;           // 15625 (exact)
    proj_kernel<<<blocks, 256, 0, stream>>>(x, out);
}